// Round 1
// baseline (6770.989 us; speedup 1.0000x reference)
//
#include <hip/hip_runtime.h>
#include <hip/hip_fp16.h>
#include <math.h>

typedef _Float16 h16;
typedef __attribute__((ext_vector_type(8))) _Float16 h16x8;
typedef __attribute__((ext_vector_type(4))) float f32x4;

static constexpr int CB   = 1024;   // C
static constexpr int TTOT = 2048;   // T
static constexpr int BBAT = 16;     // B
static constexpr int NCHK = 128;    // chunks
static constexpr int HH   = 8;
static constexpr int DHD  = 128;
static constexpr int DD   = 96;
static constexpr int NEMB = 2048;
static constexpr int BSL  = 4;            // batches per slice
static constexpr int MS   = BSL * TTOT;   // 8192 rows per slice
static constexpr int MB   = BBAT * NCHK;  // 2048 pass-B rows

__device__ __forceinline__ float blk_sum(float v, float* sh) {
  #pragma unroll
  for (int o = 32; o > 0; o >>= 1) v += __shfl_down(v, o);
  if ((threadIdx.x & 63) == 0) sh[threadIdx.x >> 6] = v;
  __syncthreads();
  float r = (sh[0] + sh[1]) + (sh[2] + sh[3]);
  __syncthreads();
  return r;
}

__device__ __forceinline__ void split_store(float v, h16* ph, h16* pl, size_t off) {
  h16 hi = (h16)v;
  ph[off] = hi;
  pl[off] = (h16)(v - (float)hi);
}

// ---------------- positional encoding (f64 to match np) ----------------
__global__ __launch_bounds__(256) void k_pe(float* peT) {
  int c = blockIdx.x * 256 + threadIdx.x;
  int i = c >> 1;
  double div = exp((double)(2 * i) * (-9.210340371976184 / 1024.0));
  #pragma unroll
  for (int t = 0; t < 16; t++) {
    double a = (double)t * div;
    peT[t * CB + c] = (c & 1) ? (float)cos(a) : (float)sin(a);
  }
}

// qc[t] = LN(pe[:,t]) for t=1..15 ; qc[0] = 0
__global__ __launch_bounds__(256) void k_qc(const float* __restrict__ peT,
                                            const float* __restrict__ g, const float* __restrict__ b,
                                            float* __restrict__ qc) {
  __shared__ float sh[4];
  int t = blockIdx.x, tid = threadIdx.x;
  if (t == 0) {
    #pragma unroll
    for (int i = 0; i < 4; i++) qc[tid + i * 256] = 0.f;
    return;
  }
  const float* xr = peT + t * CB;
  float v[4]; float s = 0.f;
  #pragma unroll
  for (int i = 0; i < 4; i++) { v[i] = xr[tid + i * 256]; s += v[i]; }
  float mean = blk_sum(s, sh) * (1.f / 1024.f);
  float q = 0.f;
  #pragma unroll
  for (int i = 0; i < 4; i++) { float d = v[i] - mean; q += d * d; }
  float var = blk_sum(q, sh) * (1.f / 1024.f);
  float rstd = 1.f / sqrtf(var + 1e-5f);
  #pragma unroll
  for (int i = 0; i < 4; i++) {
    int c = tid + i * 256;
    qc[t * CB + c] = (v[i] - mean) * rstd * g[c] + b[c];
  }
}

// Qc = qc @ Wq (f32 VALU, tiny).  Qc[0] = 0.
__global__ __launch_bounds__(64) void k_qcproj(const float* __restrict__ qc,
                                               const float* __restrict__ Wq, float* __restrict__ Qc) {
  int n = blockIdx.x * 64 + threadIdx.x;
  int t = blockIdx.y;
  if (t == 0) { Qc[n] = 0.f; return; }
  const float* qr = qc + t * CB;
  float s = 0.f;
  for (int c = 0; c < CB; c++) s += qr[c] * Wq[(size_t)c * CB + n];
  Qc[t * CB + n] = s;
}

// ---------------- weight prep: split f32 -> f16 hi/lo, transposed [N][K] ----------------
__global__ void k_split_tr(const float* __restrict__ W, h16* __restrict__ Th, h16* __restrict__ Tl,
                           int Kd, int Nd) {
  __shared__ float tile[32][33];
  int kb = blockIdx.x * 32, nb = blockIdx.y * 32;
  int tx = threadIdx.x, ty = threadIdx.y;
  #pragma unroll
  for (int i = 0; i < 4; i++)
    tile[ty + i * 8][tx] = W[(size_t)(kb + ty + i * 8) * Nd + nb + tx];
  __syncthreads();
  #pragma unroll
  for (int i = 0; i < 4; i++) {
    int n = nb + ty + i * 8, k = kb + tx;
    float v = tile[tx][ty + i * 8];
    h16 hi = (h16)v;
    Th[(size_t)n * Kd + k] = hi;
    Tl[(size_t)n * Kd + k] = (h16)(v - (float)hi);
  }
}

// Wd [96][1024] -> [128][1024] pairs, zero-padded rows
__global__ __launch_bounds__(256) void k_split_pad_rows(const float* __restrict__ src,
                                                        h16* __restrict__ Th, h16* __restrict__ Tl) {
  int r = blockIdx.x;
  int c = blockIdx.y * 256 + threadIdx.x;
  float v = (r < DD) ? src[(size_t)r * CB + c] : 0.f;
  split_store(v, Th, Tl, (size_t)r * CB + c);
}

// Wu [1024][96] -> [1024][128] pairs, zero-padded cols
__global__ __launch_bounds__(128) void k_split_pad_cols(const float* __restrict__ src,
                                                        h16* __restrict__ Th, h16* __restrict__ Tl) {
  int r = blockIdx.x, c = threadIdx.x;
  float v = (c < DD) ? src[(size_t)r * DD + c] : 0.f;
  split_store(v, Th, Tl, (size_t)r * 128 + c);
}

// books [4][2048][96] -> embT [4][96][2048]
__global__ void k_books(const float* __restrict__ books, float* __restrict__ embT) {
  __shared__ float tile[32][33];
  int eb = blockIdx.x * 32, kb = blockIdx.y * 32, bk = blockIdx.z;
  int tx = threadIdx.x, ty = threadIdx.y;
  const float* sb = books + (size_t)bk * NEMB * DD;
  #pragma unroll
  for (int i = 0; i < 4; i++)
    tile[ty + i * 8][tx] = sb[(size_t)(eb + ty + i * 8) * DD + kb + tx];
  __syncthreads();
  float* dT = embT + (size_t)bk * DD * NEMB;
  #pragma unroll
  for (int i = 0; i < 4; i++)
    dT[(size_t)(kb + ty + i * 8) * NEMB + eb + tx] = tile[tx][ty + i * 8];
}

__global__ __launch_bounds__(256) void k_hn(const float* __restrict__ books, float* __restrict__ hn) {
  int bk = blockIdx.x;
  int e = blockIdx.y * 256 + threadIdx.x;
  const float* r = books + ((size_t)bk * NEMB + e) * DD;
  float s = 0.f;
  for (int k = 0; k < DD; k++) s += r[k] * r[k];
  hn[bk * NEMB + e] = 0.5f * s;
}

// ---------------- input transpose: (B,C,T) slice -> rows [bl*T + t][c] ----------------
__global__ void k_tr_in(const float* __restrict__ src, float* __restrict__ dst, int b0,
                        float* __restrict__ zt0T) {
  __shared__ float tile[32][33];
  int tb = blockIdx.x * 32, cb = blockIdx.y * 32, bl = blockIdx.z;
  int gb = b0 + bl;
  int tx = threadIdx.x, ty = threadIdx.y;
  const float* s = src + (size_t)gb * CB * TTOT;
  #pragma unroll
  for (int i = 0; i < 4; i++)
    tile[ty + i * 8][tx] = s[(size_t)(cb + ty + i * 8) * TTOT + tb + tx];
  __syncthreads();
  float* d = dst + (size_t)bl * TTOT * CB;
  #pragma unroll
  for (int i = 0; i < 4; i++) {
    int t = tb + ty + i * 8;
    float v = tile[tx][ty + i * 8];
    d[(size_t)t * CB + cb + tx] = v;
    if (zt0T != nullptr && (t & 15) == 0)
      zt0T[(size_t)(gb * NCHK + (t >> 4)) * CB + cb + tx] = v;
  }
}

// ---------------- generic rowwise LN -> f16 pairs (optional pe add by row&15) ----------------
__global__ __launch_bounds__(256) void k_ln_generic(const float* __restrict__ x,
                                                    const float* __restrict__ peT,
                                                    const float* __restrict__ g, const float* __restrict__ b,
                                                    h16* __restrict__ oh, h16* __restrict__ ol) {
  __shared__ float sh[4];
  size_t row = blockIdx.x;
  int tid = threadIdx.x;
  const float* xr = x + row * CB;
  const float* pr = peT ? (peT + (int)(row & 15) * CB) : nullptr;
  float v[4]; float s = 0.f;
  #pragma unroll
  for (int i = 0; i < 4; i++) {
    int c = tid + i * 256;
    v[i] = xr[c] + (pr ? pr[c] : 0.f);
    s += v[i];
  }
  float mean = blk_sum(s, sh) * (1.f / 1024.f);
  float q = 0.f;
  #pragma unroll
  for (int i = 0; i < 4; i++) { float d = v[i] - mean; q += d * d; }
  float var = blk_sum(q, sh) * (1.f / 1024.f);
  float rstd = 1.f / sqrtf(var + 1e-5f);
  #pragma unroll
  for (int i = 0; i < 4; i++) {
    int c = tid + i * 256;
    float o = (v[i] - mean) * rstd * g[c] + b[c];
    split_store(o, oh, ol, row * CB + c);
  }
}

// r = zt - zp ; LN ; tanh ; * clip(scale) -> pairs
__global__ __launch_bounds__(256) void k_rln(const float* __restrict__ zt_, const float* __restrict__ zp_,
                                             const float* __restrict__ g, const float* __restrict__ b,
                                             const float* __restrict__ scale,
                                             h16* __restrict__ oh, h16* __restrict__ ol) {
  __shared__ float sh[4];
  size_t row = blockIdx.x;
  int tid = threadIdx.x;
  float v[4]; float s = 0.f;
  #pragma unroll
  for (int i = 0; i < 4; i++) {
    int c = tid + i * 256;
    v[i] = zt_[row * CB + c] - zp_[row * CB + c];
    s += v[i];
  }
  float mean = blk_sum(s, sh) * (1.f / 1024.f);
  float q = 0.f;
  #pragma unroll
  for (int i = 0; i < 4; i++) { float d = v[i] - mean; q += d * d; }
  float var = blk_sum(q, sh) * (1.f / 1024.f);
  float rstd = 1.f / sqrtf(var + 1e-5f);
  float sc = fminf(fmaxf(scale[0], 0.005f), 0.5f);
  #pragma unroll
  for (int i = 0; i < 4; i++) {
    int c = tid + i * 256;
    float o = (v[i] - mean) * rstd * g[c] + b[c];
    o = sc * tanhf(o);
    split_store(o, oh, ol, row * CB + c);
  }
}

// pass B: q0 = LN(carry_prev + pe[:,0]) -> f32 + pairs
__global__ __launch_bounds__(256) void k_q0ln(const float* __restrict__ carry, const float* __restrict__ peT,
                                              const float* __restrict__ g, const float* __restrict__ b,
                                              float* __restrict__ q0f, h16* __restrict__ oh, h16* __restrict__ ol) {
  __shared__ float sh[4];
  int row = blockIdx.x;
  int bb = row >> 7, ch = row & 127;
  int tid = threadIdx.x;
  const float* cr = (ch == 0) ? nullptr : (carry + ((size_t)bb * NCHK + (ch - 1)) * CB);
  float v[4]; float s = 0.f;
  #pragma unroll
  for (int i = 0; i < 4; i++) {
    int c = tid + i * 256;
    v[i] = (cr ? cr[c] : 0.f) + peT[c];
    s += v[i];
  }
  float mean = blk_sum(s, sh) * (1.f / 1024.f);
  float q = 0.f;
  #pragma unroll
  for (int i = 0; i < 4; i++) { float d = v[i] - mean; q += d * d; }
  float var = blk_sum(q, sh) * (1.f / 1024.f);
  float rstd = 1.f / sqrtf(var + 1e-5f);
  #pragma unroll
  for (int i = 0; i < 4; i++) {
    int c = tid + i * 256;
    float o = (v[i] - mean) * rstd * g[c] + b[c];
    q0f[(size_t)row * CB + c] = o;
    split_store(o, oh, ol, (size_t)row * CB + c);
  }
}

// ---------------- split-f16 GEMM: C[M][N] = A[M][K] * B[N][K]^T (3 MFMA terms) ----------------
// EPI: 0 none ; 1 +qc[(gm&15)] ; 2 +res ; 3 +bias,gelu->pairs ; 4 +bias+res ; 5 +bias
template<int EPI>
__global__ __launch_bounds__(256) void k_gemm(
    const h16* __restrict__ Ah, const h16* __restrict__ Al,
    const h16* __restrict__ Bh, const h16* __restrict__ Bl,
    int K, int Nout, float* __restrict__ Co,
    h16* __restrict__ Ph, h16* __restrict__ Pl,
    const float* __restrict__ bias, const float* __restrict__ res, int ldc) {
  __shared__ h16 sAh[128 * 32], sAl[128 * 32], sBh[128 * 32], sBl[128 * 32];
  int tid = threadIdx.x;
  int lane = tid & 63, wid = tid >> 6;
  int wm = (wid >> 1) * 64, wn = (wid & 1) * 64;
  int bx = blockIdx.x, by = blockIdx.y;
  f32x4 acc[4][4];
  #pragma unroll
  for (int i = 0; i < 4; i++)
    #pragma unroll
    for (int j = 0; j < 4; j++) acc[i][j] = (f32x4){0.f, 0.f, 0.f, 0.f};
  int nk = K >> 5;
  for (int kb = 0; kb < nk; kb++) {
    __syncthreads();
    #pragma unroll
    for (int i = 0; i < 2; i++) {
      int c = tid + i * 256;
      int rrow = c >> 2;
      int koff = (c & 3) * 8;
      size_t ga = (size_t)(by * 128 + rrow) * K + kb * 32 + koff;
      size_t gb2 = (size_t)(bx * 128 + rrow) * K + kb * 32 + koff;
      int bo = rrow * 64 + (c & 3) * 16;
      int swz = bo ^ (((bo >> 9) & 1) << 5);
      *(h16x8*)((char*)sAh + swz) = *(const h16x8*)(Ah + ga);
      *(h16x8*)((char*)sAl + swz) = *(const h16x8*)(Al + ga);
      *(h16x8*)((char*)sBh + swz) = *(const h16x8*)(Bh + gb2);
      *(h16x8*)((char*)sBl + swz) = *(const h16x8*)(Bl + gb2);
    }
    __syncthreads();
    int krow = (lane >> 4) * 16;
    h16x8 bhf[4], blf[4];
    #pragma unroll
    for (int nf = 0; nf < 4; nf++) {
      int r = wn + nf * 16 + (lane & 15);
      int bo = r * 64 + krow;
      int swz = bo ^ (((bo >> 9) & 1) << 5);
      bhf[nf] = *(const h16x8*)((const char*)sBh + swz);
      blf[nf] = *(const h16x8*)((const char*)sBl + swz);
    }
    #pragma unroll
    for (int mf = 0; mf < 4; mf++) {
      int r = wm + mf * 16 + (lane & 15);
      int bo = r * 64 + krow;
      int swz = bo ^ (((bo >> 9) & 1) << 5);
      h16x8 ah = *(const h16x8*)((const char*)sAh + swz);
      h16x8 al = *(const h16x8*)((const char*)sAl + swz);
      #pragma unroll
      for (int nf = 0; nf < 4; nf++) {
        acc[mf][nf] = __builtin_amdgcn_mfma_f32_16x16x32_f16(ah, bhf[nf], acc[mf][nf], 0, 0, 0);
        acc[mf][nf] = __builtin_amdgcn_mfma_f32_16x16x32_f16(al, bhf[nf], acc[mf][nf], 0, 0, 0);
        acc[mf][nf] = __builtin_amdgcn_mfma_f32_16x16x32_f16(ah, blf[nf], acc[mf][nf], 0, 0, 0);
      }
    }
  }
  #pragma unroll
  for (int mf = 0; mf < 4; mf++) {
    #pragma unroll
    for (int nf = 0; nf < 4; nf++) {
      #pragma unroll
      for (int r = 0; r < 4; r++) {
        int gm = by * 128 + wm + mf * 16 + (lane >> 4) * 4 + r;
        int gn = bx * 128 + wn + nf * 16 + (lane & 15);
        if (gn >= Nout) continue;
        float v = acc[mf][nf][r];
        if constexpr (EPI == 1) v += res[(gm & 15) * CB + gn];
        if constexpr (EPI == 2) v += res[(size_t)gm * ldc + gn];
        if constexpr (EPI == 3) { v += bias[gn]; v = 0.5f * v * (1.f + erff(v * 0.70710678118654752f)); }
        if constexpr (EPI == 4) v += bias[gn] + res[(size_t)gm * ldc + gn];
        if constexpr (EPI == 5) v += bias[gn];
        if constexpr (EPI == 3) {
          h16 hi = (h16)v;
          Ph[(size_t)gm * ldc + gn] = hi;
          Pl[(size_t)gm * ldc + gn] = (h16)(v - (float)hi);
        } else {
          Co[(size_t)gm * ldc + gn] = v;
        }
      }
    }
  }
}

// ---------------- attention (per b,chunk,head; 1 wave) ----------------
template<bool PB>
__global__ __launch_bounds__(64) void k_attn(
    const float* __restrict__ Km, const float* __restrict__ Vm,
    const float* __restrict__ Qsrc, h16* __restrict__ ch, h16* __restrict__ cl, int b0) {
  __shared__ float Ks[16][132];
  __shared__ float Vs[16][132];
  __shared__ float Ps[16][16];
  int chn = blockIdx.x, bl = blockIdx.y, h = blockIdx.z;
  int gb = b0 + bl;
  int tid = threadIdx.x;
  size_t rowbase = (size_t)gb * TTOT + chn * 16;
  #pragma unroll
  for (int i = 0; i < 8; i++) {
    int idx = tid + i * 64;
    int kk = idx >> 5, d4 = idx & 31;
    ((f32x4*)&Ks[kk][0])[d4] = *(const f32x4*)(Km + (rowbase + kk) * CB + h * DHD + d4 * 4);
    ((f32x4*)&Vs[kk][0])[d4] = *(const f32x4*)(Vm + (rowbase + kk) * CB + h * DHD + d4 * 4);
  }
  __syncthreads();
  int q = tid >> 2, k4 = tid & 3;
  const float* qrow;
  if constexpr (PB) qrow = Qsrc + ((size_t)gb * NCHK + chn) * CB + h * DHD;
  else              qrow = Qsrc + q * CB + h * DHD;
  float sc[4];
  #pragma unroll
  for (int j = 0; j < 4; j++) {
    int kk = k4 * 4 + j;
    float s = 0.f;
    for (int d = 0; d < DHD; d++) s += qrow[d] * Ks[kk][d];
    sc[j] = s / 11.313708498984761f;
  }
  float mx = fmaxf(fmaxf(sc[0], sc[1]), fmaxf(sc[2], sc[3]));
  mx = fmaxf(mx, __shfl_xor(mx, 1));
  mx = fmaxf(mx, __shfl_xor(mx, 2));
  float e[4], ss = 0.f;
  #pragma unroll
  for (int j = 0; j < 4; j++) { e[j] = expf(sc[j] - mx); ss += e[j]; }
  ss += __shfl_xor(ss, 1);
  ss += __shfl_xor(ss, 2);
  #pragma unroll
  for (int j = 0; j < 4; j++) Ps[q][k4 * 4 + j] = e[j] / ss;
  __syncthreads();
  int d0 = tid * 2;
  int q2beg = PB ? 0 : 1, q2end = PB ? 1 : 16;
  for (int q2 = q2beg; q2 < q2end; q2++) {
    float a0 = 0.f, a1 = 0.f;
    #pragma unroll
    for (int kk = 0; kk < 16; kk++) {
      float p = Ps[q2][kk];
      a0 += p * Vs[kk][d0];
      a1 += p * Vs[kk][d0 + 1];
    }
    size_t orow = PB ? ((size_t)gb * NCHK + chn) : ((size_t)bl * TTOT + chn * 16 + q2);
    size_t off = orow * CB + h * DHD + d0;
    split_store(a0, ch, cl, off);
    split_store(a1, ch, cl, off + 1);
  }
}

// ---------------- residual VQ (f32, exact argmax with first-index ties) ----------------
__global__ __launch_bounds__(256) void k_rvq(const float* __restrict__ rD,
                                             const float* __restrict__ embT, const float* __restrict__ hn,
                                             const float* __restrict__ books,
                                             h16* __restrict__ qdh, h16* __restrict__ qdl) {
  __shared__ float Rr[DD][16];
  __shared__ float Qs[DD][16];
  __shared__ float redS[64];
  __shared__ int   redI[64];
  __shared__ int   Idx[16];
  int t0 = blockIdx.x * 16;
  int tid = threadIdx.x;
  int lane = tid & 63, w = tid >> 6;
  for (int i = 0; i < 6; i++) {
    int idx = tid + i * 256;          // 16 * 96 = 1536
    int tt = idx / DD, kk = idx - tt * DD;
    Rr[kk][tt] = rD[(size_t)(t0 + tt) * DD + kk];
    Qs[kk][tt] = 0.f;
  }
  __syncthreads();
  for (int bk = 0; bk < 4; bk++) {
    const float* eT = embT + (size_t)bk * DD * NEMB;
    const float* hb = hn + bk * NEMB;
    float best[16]; int bidx[16];
    #pragma unroll
    for (int t = 0; t < 16; t++) { best[t] = -3.4e38f; bidx[t] = 0; }
    for (int eb = 0; eb < 4; eb++) {
      int e0 = eb * 512 + tid, e1 = e0 + 256;
      float s0[16], s1[16];
      #pragma unroll
      for (int t = 0; t < 16; t++) { s0[t] = 0.f; s1[t] = 0.f; }
      for (int kk = 0; kk < DD; kk++) {
        float w0 = eT[(size_t)kk * NEMB + e0];
        float w1 = eT[(size_t)kk * NEMB + e1];
        f32x4 r0 = *(const f32x4*)&Rr[kk][0];
        f32x4 r1 = *(const f32x4*)&Rr[kk][4];
        f32x4 r2 = *(const f32x4*)&Rr[kk][8];
        f32x4 r3 = *(const f32x4*)&Rr[kk][12];
        #pragma unroll
        for (int m = 0; m < 4; m++) {
          s0[m]      += w0 * r0[m]; s1[m]      += w1 * r0[m];
          s0[4 + m]  += w0 * r1[m]; s1[4 + m]  += w1 * r1[m];
          s0[8 + m]  += w0 * r2[m]; s1[8 + m]  += w1 * r2[m];
          s0[12 + m] += w0 * r3[m]; s1[12 + m] += w1 * r3[m];
        }
      }
      float h0 = hb[e0], h1v = hb[e1];
      #pragma unroll
      for (int t = 0; t < 16; t++) {
        float v0 = s0[t] - h0;
        if (v0 > best[t]) { best[t] = v0; bidx[t] = e0; }
        float v1 = s1[t] - h1v;
        if (v1 > best[t]) { best[t] = v1; bidx[t] = e1; }
      }
    }
    // per-token argmax reduce (first-index on ties)
    #pragma unroll
    for (int t = 0; t < 16; t++) {
      float v = best[t]; int ix = bidx[t];
      #pragma unroll
      for (int o = 32; o > 0; o >>= 1) {
        float ov = __shfl_down(v, o);
        int oi = __shfl_down(ix, o);
        if (ov > v || (ov == v && oi < ix)) { v = ov; ix = oi; }
      }
      if (lane == 0) { redS[w * 16 + t] = v; redI[w * 16 + t] = ix; }
    }
    __syncthreads();
    if (tid < 16) {
      float v = redS[tid]; int ix = redI[tid];
      #pragma unroll
      for (int ww = 1; ww < 4; ww++) {
        float ov = redS[ww * 16 + tid]; int oi = redI[ww * 16 + tid];
        if (ov > v || (ov == v && oi < ix)) { v = ov; ix = oi; }
      }
      Idx[tid] = ix;
    }
    __syncthreads();
    // q_sum = (q_sum + (q - r)) + r ; r = r - q   (exact f32 op order of the reference)
    for (int i = 0; i < 6; i++) {
      int idx = tid + i * 256;
      int tt = idx / DD, kk = idx - tt * DD;
      float qv = books[((size_t)bk * NEMB + Idx[tt]) * DD + kk];
      float r = Rr[kk][tt], qs = Qs[kk][tt];
      float t1 = qv - r;
      qs = qs + t1;
      qs = qs + r;
      r = r - qv;
      Qs[kk][tt] = qs; Rr[kk][tt] = r;
    }
    __syncthreads();
  }
  // write qD pairs, zero-padded to K=128
  for (int i = 0; i < 8; i++) {
    int idx = tid + i * 256;          // 16 * 128
    int tt = idx >> 7, kk = idx & 127;
    float v = (kk < DD) ? Qs[kk][tt] : 0.f;
    split_store(v, qdh, qdl, (size_t)(t0 + tt) * 128 + kk);
  }
}

// ---------------- output transposes / scatters ----------------
__global__ void k_tr_out(const float* __restrict__ zh, float* __restrict__ zrun,
                         float* __restrict__ carry, int b0) {
  __shared__ float tile[32][33];
  int tb = blockIdx.x * 32, cb = blockIdx.y * 32, bl = blockIdx.z;
  int gb = b0 + bl;
  int tx = threadIdx.x, ty = threadIdx.y;
  #pragma unroll
  for (int i = 0; i < 4; i++)
    tile[ty + i * 8][tx] = zh[((size_t)bl * TTOT + tb + ty + i * 8) * CB + cb + tx];
  __syncthreads();
  #pragma unroll
  for (int i = 0; i < 4; i++) {
    int c = cb + ty + i * 8;
    int t = tb + tx;
    float raw = tile[tx][ty + i * 8];
    float v = isfinite(raw) ? raw : 0.f;
    zrun[((size_t)gb * CB + c) * TTOT + t] = v;
    if ((t & 15) == 15)
      carry[((size_t)gb * NCHK + (t >> 4)) * CB + c] = raw;
  }
}

__global__ void k_tr_rd(const float* __restrict__ rd, float* __restrict__ rtok, int b0) {
  __shared__ float tile[32][33];
  int tb = blockIdx.x * 32, db = blockIdx.y * 32, bl = blockIdx.z;
  int gb = b0 + bl;
  int tx = threadIdx.x, ty = threadIdx.y;
  #pragma unroll
  for (int i = 0; i < 4; i++)
    tile[ty + i * 8][tx] = rd[((size_t)bl * TTOT + tb + ty + i * 8) * DD + db + tx];
  __syncthreads();
  #pragma unroll
  for (int i = 0; i < 4; i++) {
    int d = db + ty + i * 8;
    rtok[((size_t)gb * DD + d) * TTOT + tb + tx] = tile[tx][ty + i * 8];
  }
}

__global__ __launch_bounds__(256) void k_scat_z(const float* __restrict__ zh0, float* __restrict__ zrun) {
  int row = blockIdx.x;
  int c = blockIdx.y * 256 + threadIdx.x;
  int bb = row >> 7, ch = row & 127;
  float v = zh0[(size_t)row * CB + c];
  if (!isfinite(v)) v = 0.f;
  zrun[((size_t)bb * CB + c) * TTOT + ch * 16] = v;
}

__global__ __launch_bounds__(128) void k_scat_r(const float* __restrict__ rd0, float* __restrict__ rtok) {
  int row = blockIdx.x;
  int d = threadIdx.x;
  if (d >= DD) return;
  int bb = row >> 7, ch = row & 127;
  rtok[((size_t)bb * DD + d) * TTOT + ch * 16] = rd0[(size_t)row * DD + d];
}

// =======================================================================
extern "C" void kernel_launch(void* const* d_in, const int* in_sizes, int n_in,
                              void* d_out, int out_size, void* d_ws, size_t ws_size,
                              hipStream_t stream) {
  const float* qa     = (const float*)d_in[0];
  const float* zt     = (const float*)d_in[1];
  const float* ln_q_g = (const float*)d_in[2];
  const float* ln_q_b = (const float*)d_in[3];
  const float* ln_kv_g= (const float*)d_in[4];
  const float* ln_kv_b= (const float*)d_in[5];
  const float* Wq     = (const float*)d_in[6];
  const float* Wk     = (const float*)d_in[7];
  const float* Wv     = (const float*)d_in[8];
  const float* Wo     = (const float*)d_in[9];
  const float* ffn_g  = (const float*)d_in[10];
  const float* ffn_b  = (const float*)d_in[11];
  const float* W1     = (const float*)d_in[12];
  const float* b1     = (const float*)d_in[13];
  const float* W2     = (const float*)d_in[14];
  const float* b2     = (const float*)d_in[15];
  const float* tn_g   = (const float*)d_in[16];
  const float* tn_b   = (const float*)d_in[17];
  const float* scale  = (const float*)d_in[18];
  const float* Wd     = (const float*)d_in[19];
  const float* bd     = (const float*)d_in[20];
  const float* Wu     = (const float*)d_in[21];
  const float* bu     = (const float*)d_in[22];
  const float* books  = (const float*)d_in[23];
  float* zrun = (float*)d_out;
  float* rtok = zrun + (size_t)BBAT * CB * TTOT;

  char* wp = (char*)d_ws;
  auto alloc = [&](size_t bytes) -> char* {
    char* p = wp;
    wp += (bytes + 255) & ~(size_t)255;
    return p;
  };
  // weights (f16 pairs, [N][K])
  h16* WqTh = (h16*)alloc((size_t)CB * CB * 2);      h16* WqTl = (h16*)alloc((size_t)CB * CB * 2);
  h16* WkTh = (h16*)alloc((size_t)CB * CB * 2);      h16* WkTl = (h16*)alloc((size_t)CB * CB * 2);
  h16* WvTh = (h16*)alloc((size_t)CB * CB * 2);      h16* WvTl = (h16*)alloc((size_t)CB * CB * 2);
  h16* WoTh = (h16*)alloc((size_t)CB * CB * 2);      h16* WoTl = (h16*)alloc((size_t)CB * CB * 2);
  h16* W1Th = (h16*)alloc((size_t)2 * CB * CB * 2);  h16* W1Tl = (h16*)alloc((size_t)2 * CB * CB * 2);
  h16* W2Th = (h16*)alloc((size_t)2 * CB * CB * 2);  h16* W2Tl = (h16*)alloc((size_t)2 * CB * CB * 2);
  h16* WdTh = (h16*)alloc((size_t)128 * CB * 2);     h16* WdTl = (h16*)alloc((size_t)128 * CB * 2);
  h16* WuTh = (h16*)alloc((size_t)CB * 128 * 2);     h16* WuTl = (h16*)alloc((size_t)CB * 128 * 2);
  float* embT = (float*)alloc((size_t)4 * DD * NEMB * 4);
  float* hn   = (float*)alloc((size_t)4 * NEMB * 4);
  float* peT  = (float*)alloc((size_t)16 * CB * 4);
  float* qc   = (float*)alloc((size_t)16 * CB * 4);
  float* Qc   = (float*)alloc((size_t)16 * CB * 4);
  float* carry= (float*)alloc((size_t)BBAT * NCHK * CB * 4);
  float* zt0T = (float*)alloc((size_t)MB * CB * 4);
  float* Kbuf = (float*)alloc((size_t)BBAT * TTOT * CB * 4);
  float* Vbuf = (float*)alloc((size_t)BBAT * TTOT * CB * 4);
  // slice buffers (aliased across pipeline stages)
  float* bufA = (float*)alloc((size_t)MS * CB * 4);        // qaT -> y
  float* bufB = (float*)alloc((size_t)MS * CB * 4);        // ztT ; passB: q0f / Q0f
  h16* kvh  = (h16*)alloc((size_t)MS * CB * 2);            // kv pairs -> rN pairs ; passB q0 pairs
  h16* kvl  = (h16*)alloc((size_t)MS * CB * 2);
  h16* ctxh = (h16*)alloc((size_t)MS * CB * 2);            // ctx pairs -> yln pairs
  h16* ctxl = (h16*)alloc((size_t)MS * CB * 2);
  h16* h1h  = (h16*)alloc((size_t)MS * 2 * CB * 2);
  h16* h1l  = (h16*)alloc((size_t)MS * 2 * CB * 2);
  float* zp = (float*)alloc((size_t)MS * CB * 4);          // z_pred -> z_hat (in place)
  float* rDs= (float*)alloc((size_t)MS * DD * 4);
  h16* qdh  = (h16*)alloc((size_t)MS * 128 * 2);
  h16* qdl  = (h16*)alloc((size_t)MS * 128 * 2);
  (void)in_sizes; (void)n_in; (void)out_size; (void)ws_size;

  const dim3 TB(32, 8);
  // ---- prep ----
  k_pe<<<dim3(CB / 256), 256, 0, stream>>>(peT);
  k_qc<<<dim3(16), 256, 0, stream>>>(peT, ln_q_g, ln_q_b, qc);
  k_qcproj<<<dim3(16, 16), 64, 0, stream>>>(qc, Wq, Qc);
  k_split_tr<<<dim3(32, 32), TB, 0, stream>>>(Wq, WqTh, WqTl, CB, CB);
  k_split_tr<<<dim3(32, 32), TB, 0, stream>>>(Wk, WkTh, WkTl, CB, CB);
  k_split_tr<<<dim3(32, 32), TB, 0, stream>>>(Wv, WvTh, WvTl, CB, CB);
  k_split_tr<<<dim3(32, 32), TB, 0, stream>>>(Wo, WoTh, WoTl, CB, CB);
  k_split_tr<<<dim3(32, 64), TB, 0, stream>>>(W1, W1Th, W1Tl, CB, 2 * CB);
  k_split_tr<<<dim3(64, 32), TB, 0, stream>>>(W2, W2Th, W2Tl, 2 * CB, CB);
  k_split_pad_rows<<<dim3(128, 4), 256, 0, stream>>>(Wd, WdTh, WdTl);
  k_split_pad_cols<<<dim3(CB), 128, 0, stream>>>(Wu, WuTh, WuTl);
  k_books<<<dim3(64, 3, 4), TB, 0, stream>>>(books, embT);
  k_hn<<<dim3(4, 8), 256, 0, stream>>>(books, hn);

  // ---- pass A: tokens 1..15 of every chunk (t=0 rows computed on junk, overwritten in pass B) ----
  for (int s4 = 0; s4 < 4; s4++) {
    int b0 = s4 * BSL;
    k_tr_in<<<dim3(64, 32, BSL), TB, 0, stream>>>(qa, bufA, b0, nullptr);
    k_tr_in<<<dim3(64, 32, BSL), TB, 0, stream>>>(zt, bufB, b0, zt0T);
    k_ln_generic<<<dim3(MS), 256, 0, stream>>>(bufA, peT, ln_kv_g, ln_kv_b, kvh, kvl);
    k_gemm<0><<<dim3(8, 64), 256, 0, stream>>>(kvh, kvl, WkTh, WkTl, CB, CB,
        Kbuf + (size_t)b0 * TTOT * CB, nullptr, nullptr, nullptr, nullptr, CB);
    k_gemm<0><<<dim3(8, 64), 256, 0, stream>>>(kvh, kvl, WvTh, WvTl, CB, CB,
        Vbuf + (size_t)b0 * TTOT * CB, nullptr, nullptr, nullptr, nullptr, CB);
    k_attn<false><<<dim3(NCHK, BSL, HH), 64, 0, stream>>>(Kbuf, Vbuf, Qc, ctxh, ctxl, b0);
    k_gemm<1><<<dim3(8, 64), 256, 0, stream>>>(ctxh, ctxl, WoTh, WoTl, CB, CB,
        bufA, nullptr, nullptr, nullptr, qc, CB);                     // y = ctx@Wo + qc[t]
    k_ln_generic<<<dim3(MS), 256, 0, stream>>>(bufA, nullptr, ffn_g, ffn_b, ctxh, ctxl); // yln
    k_gemm<3><<<dim3(16, 64), 256, 0, stream>>>(ctxh, ctxl, W1Th, W1Tl, CB, 2 * CB,
        nullptr, h1h, h1l, b1, nullptr, 2 * CB);                      // h1 = gelu(yln@W1+b1)
    k_gemm<4><<<dim3(8, 64), 256, 0, stream>>>(h1h, h1l, W2Th, W2Tl, 2 * CB, CB,
        zp, nullptr, nullptr, b2, bufA, CB);                          // z_pred
    k_rln<<<dim3(MS), 256, 0, stream>>>(bufB, zp, tn_g, tn_b, scale, kvh, kvl);  // sc*tanh(LN(zt-zp))
    k_gemm<5><<<dim3(1, 64), 256, 0, stream>>>(kvh, kvl, WdTh, WdTl, CB, DD,
        rDs, nullptr, nullptr, bd, nullptr, DD);                      // rD
    k_rvq<<<dim3(MS / 16), 256, 0, stream>>>(rDs, embT, hn, books, qdh, qdl);
    k_gemm<4><<<dim3(8, 64), 256, 0, stream>>>(qdh, qdl, WuTh, WuTl, 128, CB,
        zp, nullptr, nullptr, bu, zp, CB);                            // z_hat (in place)
    k_tr_out<<<dim3(64, 32, BSL), TB, 0, stream>>>(zp, zrun, carry, b0);
    k_tr_rd<<<dim3(64, 3, BSL), TB, 0, stream>>>(rDs, rtok, b0);
  }

  // ---- pass B: token 0 of every chunk, using carries ----
  float* q0f = bufB;
  float* Q0f = bufB + (size_t)MB * CB;
  k_q0ln<<<dim3(MB), 256, 0, stream>>>(carry, peT, ln_q_g, ln_q_b, q0f, kvh, kvl);
  k_gemm<0><<<dim3(8, 16), 256, 0, stream>>>(kvh, kvl, WqTh, WqTl, CB, CB,
      Q0f, nullptr, nullptr, nullptr, nullptr, CB);
  k_attn<true><<<dim3(NCHK, BBAT, HH), 64, 0, stream>>>(Kbuf, Vbuf, Q0f, ctxh, ctxl, 0);
  k_gemm<2><<<dim3(8, 16), 256, 0, stream>>>(ctxh, ctxl, WoTh, WoTl, CB, CB,
      bufA, nullptr, nullptr, nullptr, q0f, CB);                      // y0 = ctx0@Wo + q0
  k_ln_generic<<<dim3(MB), 256, 0, stream>>>(bufA, nullptr, ffn_g, ffn_b, ctxh, ctxl);
  k_gemm<3><<<dim3(16, 16), 256, 0, stream>>>(ctxh, ctxl, W1Th, W1Tl, CB, 2 * CB,
      nullptr, h1h, h1l, b1, nullptr, 2 * CB);
  k_gemm<4><<<dim3(8, 16), 256, 0, stream>>>(h1h, h1l, W2Th, W2Tl, 2 * CB, CB,
      zp, nullptr, nullptr, b2, bufA, CB);
  k_rln<<<dim3(MB), 256, 0, stream>>>(zt0T, zp, tn_g, tn_b, scale, kvh, kvl);
  k_gemm<5><<<dim3(1, 16), 256, 0, stream>>>(kvh, kvl, WdTh, WdTl, CB, DD,
      rDs, nullptr, nullptr, bd, nullptr, DD);
  k_rvq<<<dim3(MB / 16), 256, 0, stream>>>(rDs, embT, hn, books, qdh, qdl);
  k_gemm<4><<<dim3(8, 16), 256, 0, stream>>>(qdh, qdl, WuTh, WuTl, 128, CB,
      zp, nullptr, nullptr, bu, zp, CB);
  k_scat_z<<<dim3(MB, 4), 256, 0, stream>>>(zp, zrun);
  k_scat_r<<<dim3(MB), 128, 0, stream>>>(rDs, rtok);
}

// Round 2
// 4153.349 us; speedup vs baseline: 1.6302x; 1.6302x over previous
//
#include <hip/hip_runtime.h>
#include <hip/hip_fp16.h>
#include <math.h>

typedef _Float16 h16;
typedef __attribute__((ext_vector_type(8))) _Float16 h16x8;
typedef __attribute__((ext_vector_type(4))) float f32x4;

static constexpr int CB   = 1024;   // C
static constexpr int TTOT = 2048;   // T
static constexpr int BBAT = 16;     // B
static constexpr int NCHK = 128;    // chunks
static constexpr int HH   = 8;
static constexpr int DHD  = 128;
static constexpr int DD   = 96;
static constexpr int NEMB = 2048;
static constexpr int BSL  = 4;            // batches per slice
static constexpr int MS   = BSL * TTOT;   // 8192 rows per slice
static constexpr int MB   = BBAT * NCHK;  // 2048 pass-B rows

__device__ __forceinline__ float blk_sum(float v, float* sh) {
  #pragma unroll
  for (int o = 32; o > 0; o >>= 1) v += __shfl_down(v, o);
  if ((threadIdx.x & 63) == 0) sh[threadIdx.x >> 6] = v;
  __syncthreads();
  float r = (sh[0] + sh[1]) + (sh[2] + sh[3]);
  __syncthreads();
  return r;
}

__device__ __forceinline__ void split_store(float v, h16* ph, h16* pl, size_t off) {
  h16 hi = (h16)v;
  ph[off] = hi;
  pl[off] = (h16)(v - (float)hi);
}

// ---------------- positional encoding (f64 to match np) ----------------
__global__ __launch_bounds__(256) void k_pe(float* peT) {
  int c = blockIdx.x * 256 + threadIdx.x;
  int i = c >> 1;
  double div = exp((double)(2 * i) * (-9.210340371976184 / 1024.0));
  #pragma unroll
  for (int t = 0; t < 16; t++) {
    double a = (double)t * div;
    peT[t * CB + c] = (c & 1) ? (float)cos(a) : (float)sin(a);
  }
}

// qc[t] = LN(pe[:,t]) for t=1..15 ; qc[0] = 0
__global__ __launch_bounds__(256) void k_qc(const float* __restrict__ peT,
                                            const float* __restrict__ g, const float* __restrict__ b,
                                            float* __restrict__ qc) {
  __shared__ float sh[4];
  int t = blockIdx.x, tid = threadIdx.x;
  if (t == 0) {
    #pragma unroll
    for (int i = 0; i < 4; i++) qc[tid + i * 256] = 0.f;
    return;
  }
  const float* xr = peT + t * CB;
  float v[4]; float s = 0.f;
  #pragma unroll
  for (int i = 0; i < 4; i++) { v[i] = xr[tid + i * 256]; s += v[i]; }
  float mean = blk_sum(s, sh) * (1.f / 1024.f);
  float q = 0.f;
  #pragma unroll
  for (int i = 0; i < 4; i++) { float d = v[i] - mean; q += d * d; }
  float var = blk_sum(q, sh) * (1.f / 1024.f);
  float rstd = 1.f / sqrtf(var + 1e-5f);
  #pragma unroll
  for (int i = 0; i < 4; i++) {
    int c = tid + i * 256;
    qc[t * CB + c] = (v[i] - mean) * rstd * g[c] + b[c];
  }
}

// Qc = qc @ Wq (f32 VALU, tiny).  Qc[0] = 0.
__global__ __launch_bounds__(64) void k_qcproj(const float* __restrict__ qc,
                                               const float* __restrict__ Wq, float* __restrict__ Qc) {
  int n = blockIdx.x * 64 + threadIdx.x;
  int t = blockIdx.y;
  if (t == 0) { Qc[n] = 0.f; return; }
  const float* qr = qc + t * CB;
  float s = 0.f;
  for (int c = 0; c < CB; c++) s += qr[c] * Wq[(size_t)c * CB + n];
  Qc[t * CB + n] = s;
}

// ---------------- weight prep: split f32 -> f16 hi/lo, transposed [N][K] ----------------
__global__ void k_split_tr(const float* __restrict__ W, h16* __restrict__ Th, h16* __restrict__ Tl,
                           int Kd, int Nd) {
  __shared__ float tile[32][33];
  int kb = blockIdx.x * 32, nb = blockIdx.y * 32;
  int tx = threadIdx.x, ty = threadIdx.y;
  #pragma unroll
  for (int i = 0; i < 4; i++)
    tile[ty + i * 8][tx] = W[(size_t)(kb + ty + i * 8) * Nd + nb + tx];
  __syncthreads();
  #pragma unroll
  for (int i = 0; i < 4; i++) {
    int n = nb + ty + i * 8, k = kb + tx;
    float v = tile[tx][ty + i * 8];
    h16 hi = (h16)v;
    Th[(size_t)n * Kd + k] = hi;
    Tl[(size_t)n * Kd + k] = (h16)(v - (float)hi);
  }
}

// Wd [96][1024] -> [128][1024] pairs, zero-padded rows
__global__ __launch_bounds__(256) void k_split_pad_rows(const float* __restrict__ src,
                                                        h16* __restrict__ Th, h16* __restrict__ Tl) {
  int r = blockIdx.x;
  int c = blockIdx.y * 256 + threadIdx.x;
  float v = (r < DD) ? src[(size_t)r * CB + c] : 0.f;
  split_store(v, Th, Tl, (size_t)r * CB + c);
}

// Wu [1024][96] -> [1024][128] pairs, zero-padded cols
__global__ __launch_bounds__(128) void k_split_pad_cols(const float* __restrict__ src,
                                                        h16* __restrict__ Th, h16* __restrict__ Tl) {
  int r = blockIdx.x, c = threadIdx.x;
  float v = (c < DD) ? src[(size_t)r * DD + c] : 0.f;
  split_store(v, Th, Tl, (size_t)r * 128 + c);
}

// books [4][2048][96] -> MFMA-fragment-ordered split-f16 codebooks
// layout: offset(bk,ct,ks,lane,j) = (((bk*128+ct)*3+ks)*64+lane)*8+j
//   where code = ct*16+(lane&15), k = ks*32+(lane>>4)*8+j
__global__ __launch_bounds__(64) void k_bookfrag(const float* __restrict__ books,
                                                 h16* __restrict__ Fh, h16* __restrict__ Fl) {
  int ct = blockIdx.x, ks = blockIdx.y, bk = blockIdx.z;
  int lane = threadIdx.x;
  int code = ct * 16 + (lane & 15);
  int kb = ks * 32 + (lane >> 4) * 8;
  const float* src = books + ((size_t)bk * NEMB + code) * DD + kb;
  size_t off = ((size_t)((bk * 128 + ct) * 3 + ks) * 64 + lane) * 8;
  #pragma unroll
  for (int j = 0; j < 8; j++) {
    float v = src[j];
    h16 hi = (h16)v;
    Fh[off + j] = hi;
    Fl[off + j] = (h16)(v - (float)hi);
  }
}

__global__ __launch_bounds__(256) void k_hn(const float* __restrict__ books, float* __restrict__ hn) {
  int bk = blockIdx.x;
  int e = blockIdx.y * 256 + threadIdx.x;
  const float* r = books + ((size_t)bk * NEMB + e) * DD;
  float s = 0.f;
  for (int k = 0; k < DD; k++) s += r[k] * r[k];
  hn[bk * NEMB + e] = 0.5f * s;
}

// ---------------- input transpose: (B,C,T) slice -> rows [bl*T + t][c] ----------------
__global__ void k_tr_in(const float* __restrict__ src, float* __restrict__ dst, int b0,
                        float* __restrict__ zt0T) {
  __shared__ float tile[32][33];
  int tb = blockIdx.x * 32, cb = blockIdx.y * 32, bl = blockIdx.z;
  int gb = b0 + bl;
  int tx = threadIdx.x, ty = threadIdx.y;
  const float* s = src + (size_t)gb * CB * TTOT;
  #pragma unroll
  for (int i = 0; i < 4; i++)
    tile[ty + i * 8][tx] = s[(size_t)(cb + ty + i * 8) * TTOT + tb + tx];
  __syncthreads();
  float* d = dst + (size_t)bl * TTOT * CB;
  #pragma unroll
  for (int i = 0; i < 4; i++) {
    int t = tb + ty + i * 8;
    float v = tile[tx][ty + i * 8];
    d[(size_t)t * CB + cb + tx] = v;
    if (zt0T != nullptr && (t & 15) == 0)
      zt0T[(size_t)(gb * NCHK + (t >> 4)) * CB + cb + tx] = v;
  }
}

// ---------------- generic rowwise LN -> f16 pairs (optional pe add by row&15) ----------------
__global__ __launch_bounds__(256) void k_ln_generic(const float* __restrict__ x,
                                                    const float* __restrict__ peT,
                                                    const float* __restrict__ g, const float* __restrict__ b,
                                                    h16* __restrict__ oh, h16* __restrict__ ol) {
  __shared__ float sh[4];
  size_t row = blockIdx.x;
  int tid = threadIdx.x;
  const float* xr = x + row * CB;
  const float* pr = peT ? (peT + (int)(row & 15) * CB) : nullptr;
  float v[4]; float s = 0.f;
  #pragma unroll
  for (int i = 0; i < 4; i++) {
    int c = tid + i * 256;
    v[i] = xr[c] + (pr ? pr[c] : 0.f);
    s += v[i];
  }
  float mean = blk_sum(s, sh) * (1.f / 1024.f);
  float q = 0.f;
  #pragma unroll
  for (int i = 0; i < 4; i++) { float d = v[i] - mean; q += d * d; }
  float var = blk_sum(q, sh) * (1.f / 1024.f);
  float rstd = 1.f / sqrtf(var + 1e-5f);
  #pragma unroll
  for (int i = 0; i < 4; i++) {
    int c = tid + i * 256;
    float o = (v[i] - mean) * rstd * g[c] + b[c];
    split_store(o, oh, ol, row * CB + c);
  }
}

// r = zt - zp ; LN ; tanh ; * clip(scale) -> pairs
__global__ __launch_bounds__(256) void k_rln(const float* __restrict__ zt_, const float* __restrict__ zp_,
                                             const float* __restrict__ g, const float* __restrict__ b,
                                             const float* __restrict__ scale,
                                             h16* __restrict__ oh, h16* __restrict__ ol) {
  __shared__ float sh[4];
  size_t row = blockIdx.x;
  int tid = threadIdx.x;
  float v[4]; float s = 0.f;
  #pragma unroll
  for (int i = 0; i < 4; i++) {
    int c = tid + i * 256;
    v[i] = zt_[row * CB + c] - zp_[row * CB + c];
    s += v[i];
  }
  float mean = blk_sum(s, sh) * (1.f / 1024.f);
  float q = 0.f;
  #pragma unroll
  for (int i = 0; i < 4; i++) { float d = v[i] - mean; q += d * d; }
  float var = blk_sum(q, sh) * (1.f / 1024.f);
  float rstd = 1.f / sqrtf(var + 1e-5f);
  float sc = fminf(fmaxf(scale[0], 0.005f), 0.5f);
  #pragma unroll
  for (int i = 0; i < 4; i++) {
    int c = tid + i * 256;
    float o = (v[i] - mean) * rstd * g[c] + b[c];
    o = sc * tanhf(o);
    split_store(o, oh, ol, row * CB + c);
  }
}

// pass B: q0 = LN(carry_prev + pe[:,0]) -> f32 + pairs
__global__ __launch_bounds__(256) void k_q0ln(const float* __restrict__ carry, const float* __restrict__ peT,
                                              const float* __restrict__ g, const float* __restrict__ b,
                                              float* __restrict__ q0f, h16* __restrict__ oh, h16* __restrict__ ol) {
  __shared__ float sh[4];
  int row = blockIdx.x;
  int bb = row >> 7, ch = row & 127;
  int tid = threadIdx.x;
  const float* cr = (ch == 0) ? nullptr : (carry + ((size_t)bb * NCHK + (ch - 1)) * CB);
  float v[4]; float s = 0.f;
  #pragma unroll
  for (int i = 0; i < 4; i++) {
    int c = tid + i * 256;
    v[i] = (cr ? cr[c] : 0.f) + peT[c];
    s += v[i];
  }
  float mean = blk_sum(s, sh) * (1.f / 1024.f);
  float q = 0.f;
  #pragma unroll
  for (int i = 0; i < 4; i++) { float d = v[i] - mean; q += d * d; }
  float var = blk_sum(q, sh) * (1.f / 1024.f);
  float rstd = 1.f / sqrtf(var + 1e-5f);
  #pragma unroll
  for (int i = 0; i < 4; i++) {
    int c = tid + i * 256;
    float o = (v[i] - mean) * rstd * g[c] + b[c];
    q0f[(size_t)row * CB + c] = o;
    split_store(o, oh, ol, (size_t)row * CB + c);
  }
}

// ---------------- split-f16 GEMM: C[M][N] = A[M][K] * B[N][K]^T (3 MFMA terms) ----------------
// EPI: 0 none ; 1 +qc[(gm&15)] ; 2 +res ; 3 +bias,gelu->pairs ; 4 +bias+res ; 5 +bias
template<int EPI>
__global__ __launch_bounds__(256) void k_gemm(
    const h16* __restrict__ Ah, const h16* __restrict__ Al,
    const h16* __restrict__ Bh, const h16* __restrict__ Bl,
    int K, int Nout, float* __restrict__ Co,
    h16* __restrict__ Ph, h16* __restrict__ Pl,
    const float* __restrict__ bias, const float* __restrict__ res, int ldc) {
  __shared__ h16 sAh[128 * 32], sAl[128 * 32], sBh[128 * 32], sBl[128 * 32];
  int tid = threadIdx.x;
  int lane = tid & 63, wid = tid >> 6;
  int wm = (wid >> 1) * 64, wn = (wid & 1) * 64;
  int bx = blockIdx.x, by = blockIdx.y;
  f32x4 acc[4][4];
  #pragma unroll
  for (int i = 0; i < 4; i++)
    #pragma unroll
    for (int j = 0; j < 4; j++) acc[i][j] = (f32x4){0.f, 0.f, 0.f, 0.f};
  int nk = K >> 5;
  for (int kb = 0; kb < nk; kb++) {
    __syncthreads();
    #pragma unroll
    for (int i = 0; i < 2; i++) {
      int c = tid + i * 256;
      int rrow = c >> 2;
      int koff = (c & 3) * 8;
      size_t ga = (size_t)(by * 128 + rrow) * K + kb * 32 + koff;
      size_t gb2 = (size_t)(bx * 128 + rrow) * K + kb * 32 + koff;
      int bo = rrow * 64 + (c & 3) * 16;
      int swz = bo ^ (((bo >> 9) & 1) << 5);
      *(h16x8*)((char*)sAh + swz) = *(const h16x8*)(Ah + ga);
      *(h16x8*)((char*)sAl + swz) = *(const h16x8*)(Al + ga);
      *(h16x8*)((char*)sBh + swz) = *(const h16x8*)(Bh + gb2);
      *(h16x8*)((char*)sBl + swz) = *(const h16x8*)(Bl + gb2);
    }
    __syncthreads();
    int krow = (lane >> 4) * 16;
    h16x8 bhf[4], blf[4];
    #pragma unroll
    for (int nf = 0; nf < 4; nf++) {
      int r = wn + nf * 16 + (lane & 15);
      int bo = r * 64 + krow;
      int swz = bo ^ (((bo >> 9) & 1) << 5);
      bhf[nf] = *(const h16x8*)((const char*)sBh + swz);
      blf[nf] = *(const h16x8*)((const char*)sBl + swz);
    }
    #pragma unroll
    for (int mf = 0; mf < 4; mf++) {
      int r = wm + mf * 16 + (lane & 15);
      int bo = r * 64 + krow;
      int swz = bo ^ (((bo >> 9) & 1) << 5);
      h16x8 ah = *(const h16x8*)((const char*)sAh + swz);
      h16x8 al = *(const h16x8*)((const char*)sAl + swz);
      #pragma unroll
      for (int nf = 0; nf < 4; nf++) {
        acc[mf][nf] = __builtin_amdgcn_mfma_f32_16x16x32_f16(ah, bhf[nf], acc[mf][nf], 0, 0, 0);
        acc[mf][nf] = __builtin_amdgcn_mfma_f32_16x16x32_f16(al, bhf[nf], acc[mf][nf], 0, 0, 0);
        acc[mf][nf] = __builtin_amdgcn_mfma_f32_16x16x32_f16(ah, blf[nf], acc[mf][nf], 0, 0, 0);
      }
    }
  }
  #pragma unroll
  for (int mf = 0; mf < 4; mf++) {
    #pragma unroll
    for (int nf = 0; nf < 4; nf++) {
      #pragma unroll
      for (int r = 0; r < 4; r++) {
        int gm = by * 128 + wm + mf * 16 + (lane >> 4) * 4 + r;
        int gn = bx * 128 + wn + nf * 16 + (lane & 15);
        if (gn >= Nout) continue;
        float v = acc[mf][nf][r];
        if constexpr (EPI == 1) v += res[(gm & 15) * CB + gn];
        if constexpr (EPI == 2) v += res[(size_t)gm * ldc + gn];
        if constexpr (EPI == 3) { v += bias[gn]; v = 0.5f * v * (1.f + erff(v * 0.70710678118654752f)); }
        if constexpr (EPI == 4) v += bias[gn] + res[(size_t)gm * ldc + gn];
        if constexpr (EPI == 5) v += bias[gn];
        if constexpr (EPI == 3) {
          h16 hi = (h16)v;
          Ph[(size_t)gm * ldc + gn] = hi;
          Pl[(size_t)gm * ldc + gn] = (h16)(v - (float)hi);
        } else {
          Co[(size_t)gm * ldc + gn] = v;
        }
      }
    }
  }
}

// ---------------- attention (per b,chunk,head; 1 wave) ----------------
template<bool PB>
__global__ __launch_bounds__(64) void k_attn(
    const float* __restrict__ Km, const float* __restrict__ Vm,
    const float* __restrict__ Qsrc, h16* __restrict__ ch, h16* __restrict__ cl, int b0) {
  __shared__ float Ks[16][132];
  __shared__ float Vs[16][132];
  __shared__ float Ps[16][16];
  int chn = blockIdx.x, bl = blockIdx.y, h = blockIdx.z;
  int gb = b0 + bl;
  int tid = threadIdx.x;
  size_t rowbase = (size_t)gb * TTOT + chn * 16;
  #pragma unroll
  for (int i = 0; i < 8; i++) {
    int idx = tid + i * 64;
    int kk = idx >> 5, d4 = idx & 31;
    ((f32x4*)&Ks[kk][0])[d4] = *(const f32x4*)(Km + (rowbase + kk) * CB + h * DHD + d4 * 4);
    ((f32x4*)&Vs[kk][0])[d4] = *(const f32x4*)(Vm + (rowbase + kk) * CB + h * DHD + d4 * 4);
  }
  __syncthreads();
  int q = tid >> 2, k4 = tid & 3;
  const float* qrow;
  if constexpr (PB) qrow = Qsrc + ((size_t)gb * NCHK + chn) * CB + h * DHD;
  else              qrow = Qsrc + q * CB + h * DHD;
  float sc[4];
  #pragma unroll
  for (int j = 0; j < 4; j++) {
    int kk = k4 * 4 + j;
    float s = 0.f;
    for (int d = 0; d < DHD; d++) s += qrow[d] * Ks[kk][d];
    sc[j] = s / 11.313708498984761f;
  }
  float mx = fmaxf(fmaxf(sc[0], sc[1]), fmaxf(sc[2], sc[3]));
  mx = fmaxf(mx, __shfl_xor(mx, 1));
  mx = fmaxf(mx, __shfl_xor(mx, 2));
  float e[4], ss = 0.f;
  #pragma unroll
  for (int j = 0; j < 4; j++) { e[j] = expf(sc[j] - mx); ss += e[j]; }
  ss += __shfl_xor(ss, 1);
  ss += __shfl_xor(ss, 2);
  #pragma unroll
  for (int j = 0; j < 4; j++) Ps[q][k4 * 4 + j] = e[j] / ss;
  __syncthreads();
  int d0 = tid * 2;
  int q2beg = PB ? 0 : 1, q2end = PB ? 1 : 16;
  for (int q2 = q2beg; q2 < q2end; q2++) {
    float a0 = 0.f, a1 = 0.f;
    #pragma unroll
    for (int kk = 0; kk < 16; kk++) {
      float p = Ps[q2][kk];
      a0 += p * Vs[kk][d0];
      a1 += p * Vs[kk][d0 + 1];
    }
    size_t orow = PB ? ((size_t)gb * NCHK + chn) : ((size_t)bl * TTOT + chn * 16 + q2);
    size_t off = orow * CB + h * DHD + d0;
    split_store(a0, ch, cl, off);
    split_store(a1, ch, cl, off + 1);
  }
}

// ---------------- residual VQ v2: MFMA scores, register-resident residual ----------------
// block = 512 threads (8 waves), 16 tokens per block; wave w scans codes [w*256,(w+1)*256)
__global__ __launch_bounds__(512) void k_rvq2(
    const float* __restrict__ rD,
    const h16* __restrict__ Fh, const h16* __restrict__ Fl,
    const float* __restrict__ hn, const float* __restrict__ books,
    h16* __restrict__ qdh, h16* __restrict__ qdl) {
  __shared__ float redS[8 * 16];
  __shared__ int   redI[8 * 16];
  __shared__ int   Idx[16];
  int t0 = blockIdx.x * 16;
  int tid = threadIdx.x;
  int lane = tid & 63, wid = tid >> 6;
  int tk = lane & 15, g = lane >> 4;
  // lane-resident residual / q_sum: token tk, k = ks*32 + g*8 + {0..7}
  f32x4 rv[3][2], qs[3][2];
  #pragma unroll
  for (int ks = 0; ks < 3; ks++) {
    const f32x4* p = (const f32x4*)(rD + (size_t)(t0 + tk) * DD + ks * 32 + g * 8);
    rv[ks][0] = p[0]; rv[ks][1] = p[1];
    qs[ks][0] = (f32x4){0.f, 0.f, 0.f, 0.f};
    qs[ks][1] = (f32x4){0.f, 0.f, 0.f, 0.f};
  }
  for (int bk = 0; bk < 4; bk++) {
    // A fragments (split f16) from register residual
    h16x8 ah[3], al[3];
    #pragma unroll
    for (int ks = 0; ks < 3; ks++) {
      #pragma unroll
      for (int q = 0; q < 2; q++) {
        #pragma unroll
        for (int j = 0; j < 4; j++) {
          float v = rv[ks][q][j];
          h16 hi = (h16)v;
          ah[ks][q * 4 + j] = hi;
          al[ks][q * 4 + j] = (h16)(v - (float)hi);
        }
      }
    }
    float bestv[4]; int besti[4];
    #pragma unroll
    for (int r = 0; r < 4; r++) { bestv[r] = -3.4e38f; besti[r] = 0; }
    for (int i = 0; i < 16; i++) {
      int ct = wid * 16 + i;
      size_t fb = ((size_t)((bk * 128 + ct) * 3) * 64 + lane) * 8;
      h16x8 bh0 = *(const h16x8*)(Fh + fb);
      h16x8 bh1 = *(const h16x8*)(Fh + fb + 512);
      h16x8 bh2 = *(const h16x8*)(Fh + fb + 1024);
      h16x8 bl0 = *(const h16x8*)(Fl + fb);
      h16x8 bl1 = *(const h16x8*)(Fl + fb + 512);
      h16x8 bl2 = *(const h16x8*)(Fl + fb + 1024);
      float hnv = hn[bk * NEMB + ct * 16 + tk];
      f32x4 acc = (f32x4){0.f, 0.f, 0.f, 0.f};
      acc = __builtin_amdgcn_mfma_f32_16x16x32_f16(ah[0], bh0, acc, 0, 0, 0);
      acc = __builtin_amdgcn_mfma_f32_16x16x32_f16(al[0], bh0, acc, 0, 0, 0);
      acc = __builtin_amdgcn_mfma_f32_16x16x32_f16(ah[0], bl0, acc, 0, 0, 0);
      acc = __builtin_amdgcn_mfma_f32_16x16x32_f16(al[0], bl0, acc, 0, 0, 0);
      acc = __builtin_amdgcn_mfma_f32_16x16x32_f16(ah[1], bh1, acc, 0, 0, 0);
      acc = __builtin_amdgcn_mfma_f32_16x16x32_f16(al[1], bh1, acc, 0, 0, 0);
      acc = __builtin_amdgcn_mfma_f32_16x16x32_f16(ah[1], bl1, acc, 0, 0, 0);
      acc = __builtin_amdgcn_mfma_f32_16x16x32_f16(al[1], bl1, acc, 0, 0, 0);
      acc = __builtin_amdgcn_mfma_f32_16x16x32_f16(ah[2], bh2, acc, 0, 0, 0);
      acc = __builtin_amdgcn_mfma_f32_16x16x32_f16(al[2], bh2, acc, 0, 0, 0);
      acc = __builtin_amdgcn_mfma_f32_16x16x32_f16(ah[2], bl2, acc, 0, 0, 0);
      acc = __builtin_amdgcn_mfma_f32_16x16x32_f16(al[2], bl2, acc, 0, 0, 0);
      // acc[r] = score[token g*4+r][code ct*16+tk]
      int code = ct * 16 + tk;
      #pragma unroll
      for (int r = 0; r < 4; r++) {
        float v = acc[r] - hnv;
        if (v > bestv[r]) { bestv[r] = v; besti[r] = code; }
      }
    }
    // reduce across the 16 lanes of each g-group (tokens g*4+r), first-index ties
    #pragma unroll
    for (int r = 0; r < 4; r++) {
      float v = bestv[r]; int ix = besti[r];
      #pragma unroll
      for (int o = 1; o < 16; o <<= 1) {
        float ov = __shfl_xor(v, o);
        int oi = __shfl_xor(ix, o);
        if (ov > v || (ov == v && oi < ix)) { v = ov; ix = oi; }
      }
      if (tk == 0) { redS[wid * 16 + g * 4 + r] = v; redI[wid * 16 + g * 4 + r] = ix; }
    }
    __syncthreads();
    if (tid < 16) {
      float v = redS[tid]; int ix = redI[tid];
      #pragma unroll
      for (int w = 1; w < 8; w++) {
        float ov = redS[w * 16 + tid]; int oi = redI[w * 16 + tid];
        if (ov > v || (ov == v && oi < ix)) { v = ov; ix = oi; }
      }
      Idx[tid] = ix;
    }
    __syncthreads();
    // residual update, exact reference f32 op order
    int sel = Idx[tk];
    const float* bp = books + ((size_t)bk * NEMB + sel) * DD;
    #pragma unroll
    for (int ks = 0; ks < 3; ks++) {
      #pragma unroll
      for (int q = 0; q < 2; q++) {
        f32x4 qv = *(const f32x4*)(bp + ks * 32 + g * 8 + q * 4);
        #pragma unroll
        for (int j = 0; j < 4; j++) {
          float r0 = rv[ks][q][j], q0 = qs[ks][q][j], qvj = qv[j];
          float t1 = qvj - r0;
          q0 = q0 + t1;
          q0 = q0 + r0;
          r0 = r0 - qvj;
          qs[ks][q][j] = q0; rv[ks][q][j] = r0;
        }
      }
    }
    __syncthreads();
  }
  // write qD split pairs (wave 0: data, wave 1: zero pad k=96..127)
  if (wid == 0) {
    #pragma unroll
    for (int ks = 0; ks < 3; ks++) {
      #pragma unroll
      for (int q = 0; q < 2; q++) {
        size_t off = (size_t)(t0 + tk) * 128 + ks * 32 + g * 8 + q * 4;
        #pragma unroll
        for (int j = 0; j < 4; j++) {
          float v = qs[ks][q][j];
          h16 hi = (h16)v;
          qdh[off + j] = hi;
          qdl[off + j] = (h16)(v - (float)hi);
        }
      }
    }
  } else if (wid == 1) {
    size_t off = (size_t)(t0 + tk) * 128 + 96 + g * 8;
    #pragma unroll
    for (int j = 0; j < 8; j++) { qdh[off + j] = (h16)0.f; qdl[off + j] = (h16)0.f; }
  }
}

// ---------------- output transposes / scatters ----------------
__global__ void k_tr_out(const float* __restrict__ zh, float* __restrict__ zrun,
                         float* __restrict__ carry, int b0) {
  __shared__ float tile[32][33];
  int tb = blockIdx.x * 32, cb = blockIdx.y * 32, bl = blockIdx.z;
  int gb = b0 + bl;
  int tx = threadIdx.x, ty = threadIdx.y;
  #pragma unroll
  for (int i = 0; i < 4; i++)
    tile[ty + i * 8][tx] = zh[((size_t)bl * TTOT + tb + ty + i * 8) * CB + cb + tx];
  __syncthreads();
  #pragma unroll
  for (int i = 0; i < 4; i++) {
    int c = cb + ty + i * 8;
    int t = tb + tx;
    float raw = tile[tx][ty + i * 8];
    float v = isfinite(raw) ? raw : 0.f;
    zrun[((size_t)gb * CB + c) * TTOT + t] = v;
    if ((t & 15) == 15)
      carry[((size_t)gb * NCHK + (t >> 4)) * CB + c] = raw;
  }
}

__global__ void k_tr_rd(const float* __restrict__ rd, float* __restrict__ rtok, int b0) {
  __shared__ float tile[32][33];
  int tb = blockIdx.x * 32, db = blockIdx.y * 32, bl = blockIdx.z;
  int gb = b0 + bl;
  int tx = threadIdx.x, ty = threadIdx.y;
  #pragma unroll
  for (int i = 0; i < 4; i++)
    tile[ty + i * 8][tx] = rd[((size_t)bl * TTOT + tb + ty + i * 8) * DD + db + tx];
  __syncthreads();
  #pragma unroll
  for (int i = 0; i < 4; i++) {
    int d = db + ty + i * 8;
    rtok[((size_t)gb * DD + d) * TTOT + tb + tx] = tile[tx][ty + i * 8];
  }
}

__global__ __launch_bounds__(256) void k_scat_z(const float* __restrict__ zh0, float* __restrict__ zrun) {
  int row = blockIdx.x;
  int c = blockIdx.y * 256 + threadIdx.x;
  int bb = row >> 7, ch = row & 127;
  float v = zh0[(size_t)row * CB + c];
  if (!isfinite(v)) v = 0.f;
  zrun[((size_t)bb * CB + c) * TTOT + ch * 16] = v;
}

__global__ __launch_bounds__(128) void k_scat_r(const float* __restrict__ rd0, float* __restrict__ rtok) {
  int row = blockIdx.x;
  int d = threadIdx.x;
  if (d >= DD) return;
  int bb = row >> 7, ch = row & 127;
  rtok[((size_t)bb * DD + d) * TTOT + ch * 16] = rd0[(size_t)row * DD + d];
}

// =======================================================================
extern "C" void kernel_launch(void* const* d_in, const int* in_sizes, int n_in,
                              void* d_out, int out_size, void* d_ws, size_t ws_size,
                              hipStream_t stream) {
  const float* qa     = (const float*)d_in[0];
  const float* zt     = (const float*)d_in[1];
  const float* ln_q_g = (const float*)d_in[2];
  const float* ln_q_b = (const float*)d_in[3];
  const float* ln_kv_g= (const float*)d_in[4];
  const float* ln_kv_b= (const float*)d_in[5];
  const float* Wq     = (const float*)d_in[6];
  const float* Wk     = (const float*)d_in[7];
  const float* Wv     = (const float*)d_in[8];
  const float* Wo     = (const float*)d_in[9];
  const float* ffn_g  = (const float*)d_in[10];
  const float* ffn_b  = (const float*)d_in[11];
  const float* W1     = (const float*)d_in[12];
  const float* b1     = (const float*)d_in[13];
  const float* W2     = (const float*)d_in[14];
  const float* b2     = (const float*)d_in[15];
  const float* tn_g   = (const float*)d_in[16];
  const float* tn_b   = (const float*)d_in[17];
  const float* scale  = (const float*)d_in[18];
  const float* Wd     = (const float*)d_in[19];
  const float* bd     = (const float*)d_in[20];
  const float* Wu     = (const float*)d_in[21];
  const float* bu     = (const float*)d_in[22];
  const float* books  = (const float*)d_in[23];
  float* zrun = (float*)d_out;
  float* rtok = zrun + (size_t)BBAT * CB * TTOT;

  char* wp = (char*)d_ws;
  auto alloc = [&](size_t bytes) -> char* {
    char* p = wp;
    wp += (bytes + 255) & ~(size_t)255;
    return p;
  };
  // weights (f16 pairs, [N][K])
  h16* WqTh = (h16*)alloc((size_t)CB * CB * 2);      h16* WqTl = (h16*)alloc((size_t)CB * CB * 2);
  h16* WkTh = (h16*)alloc((size_t)CB * CB * 2);      h16* WkTl = (h16*)alloc((size_t)CB * CB * 2);
  h16* WvTh = (h16*)alloc((size_t)CB * CB * 2);      h16* WvTl = (h16*)alloc((size_t)CB * CB * 2);
  h16* WoTh = (h16*)alloc((size_t)CB * CB * 2);      h16* WoTl = (h16*)alloc((size_t)CB * CB * 2);
  h16* W1Th = (h16*)alloc((size_t)2 * CB * CB * 2);  h16* W1Tl = (h16*)alloc((size_t)2 * CB * CB * 2);
  h16* W2Th = (h16*)alloc((size_t)2 * CB * CB * 2);  h16* W2Tl = (h16*)alloc((size_t)2 * CB * CB * 2);
  h16* WdTh = (h16*)alloc((size_t)128 * CB * 2);     h16* WdTl = (h16*)alloc((size_t)128 * CB * 2);
  h16* WuTh = (h16*)alloc((size_t)CB * 128 * 2);     h16* WuTl = (h16*)alloc((size_t)CB * 128 * 2);
  // codebooks: fragment-ordered split-f16 + hn
  h16* bookFh = (h16*)alloc((size_t)4 * 128 * 3 * 64 * 8 * 2);
  h16* bookFl = (h16*)alloc((size_t)4 * 128 * 3 * 64 * 8 * 2);
  float* hn   = (float*)alloc((size_t)4 * NEMB * 4);
  float* peT  = (float*)alloc((size_t)16 * CB * 4);
  float* qc   = (float*)alloc((size_t)16 * CB * 4);
  float* Qc   = (float*)alloc((size_t)16 * CB * 4);
  float* carry= (float*)alloc((size_t)BBAT * NCHK * CB * 4);
  float* zt0T = (float*)alloc((size_t)MB * CB * 4);
  float* Kbuf = (float*)alloc((size_t)BBAT * TTOT * CB * 4);
  float* Vbuf = (float*)alloc((size_t)BBAT * TTOT * CB * 4);
  // slice buffers (aliased across pipeline stages)
  float* bufA = (float*)alloc((size_t)MS * CB * 4);        // qaT -> y
  float* bufB = (float*)alloc((size_t)MS * CB * 4);        // ztT ; passB: q0f / Q0f
  h16* kvh  = (h16*)alloc((size_t)MS * CB * 2);            // kv pairs -> rN pairs ; passB q0 pairs
  h16* kvl  = (h16*)alloc((size_t)MS * CB * 2);
  h16* ctxh = (h16*)alloc((size_t)MS * CB * 2);            // ctx pairs -> yln pairs
  h16* ctxl = (h16*)alloc((size_t)MS * CB * 2);
  h16* h1h  = (h16*)alloc((size_t)MS * 2 * CB * 2);
  h16* h1l  = (h16*)alloc((size_t)MS * 2 * CB * 2);
  float* zp = (float*)alloc((size_t)MS * CB * 4);          // z_pred -> z_hat (in place)
  float* rDs= (float*)alloc((size_t)MS * DD * 4);
  h16* qdh  = (h16*)alloc((size_t)MS * 128 * 2);
  h16* qdl  = (h16*)alloc((size_t)MS * 128 * 2);
  (void)in_sizes; (void)n_in; (void)out_size; (void)ws_size;

  const dim3 TB(32, 8);
  // ---- prep ----
  k_pe<<<dim3(CB / 256), 256, 0, stream>>>(peT);
  k_qc<<<dim3(16), 256, 0, stream>>>(peT, ln_q_g, ln_q_b, qc);
  k_qcproj<<<dim3(16, 16), 64, 0, stream>>>(qc, Wq, Qc);
  k_split_tr<<<dim3(32, 32), TB, 0, stream>>>(Wq, WqTh, WqTl, CB, CB);
  k_split_tr<<<dim3(32, 32), TB, 0, stream>>>(Wk, WkTh, WkTl, CB, CB);
  k_split_tr<<<dim3(32, 32), TB, 0, stream>>>(Wv, WvTh, WvTl, CB, CB);
  k_split_tr<<<dim3(32, 32), TB, 0, stream>>>(Wo, WoTh, WoTl, CB, CB);
  k_split_tr<<<dim3(32, 64), TB, 0, stream>>>(W1, W1Th, W1Tl, CB, 2 * CB);
  k_split_tr<<<dim3(64, 32), TB, 0, stream>>>(W2, W2Th, W2Tl, 2 * CB, CB);
  k_split_pad_rows<<<dim3(128, 4), 256, 0, stream>>>(Wd, WdTh, WdTl);
  k_split_pad_cols<<<dim3(CB), 128, 0, stream>>>(Wu, WuTh, WuTl);
  k_bookfrag<<<dim3(128, 3, 4), 64, 0, stream>>>(books, bookFh, bookFl);
  k_hn<<<dim3(4, 8), 256, 0, stream>>>(books, hn);

  // ---- pass A: tokens 1..15 of every chunk (t=0 rows computed on junk, overwritten in pass B) ----
  for (int s4 = 0; s4 < 4; s4++) {
    int b0 = s4 * BSL;
    k_tr_in<<<dim3(64, 32, BSL), TB, 0, stream>>>(qa, bufA, b0, nullptr);
    k_tr_in<<<dim3(64, 32, BSL), TB, 0, stream>>>(zt, bufB, b0, zt0T);
    k_ln_generic<<<dim3(MS), 256, 0, stream>>>(bufA, peT, ln_kv_g, ln_kv_b, kvh, kvl);
    k_gemm<0><<<dim3(8, 64), 256, 0, stream>>>(kvh, kvl, WkTh, WkTl, CB, CB,
        Kbuf + (size_t)b0 * TTOT * CB, nullptr, nullptr, nullptr, nullptr, CB);
    k_gemm<0><<<dim3(8, 64), 256, 0, stream>>>(kvh, kvl, WvTh, WvTl, CB, CB,
        Vbuf + (size_t)b0 * TTOT * CB, nullptr, nullptr, nullptr, nullptr, CB);
    k_attn<false><<<dim3(NCHK, BSL, HH), 64, 0, stream>>>(Kbuf, Vbuf, Qc, ctxh, ctxl, b0);
    k_gemm<1><<<dim3(8, 64), 256, 0, stream>>>(ctxh, ctxl, WoTh, WoTl, CB, CB,
        bufA, nullptr, nullptr, nullptr, qc, CB);                     // y = ctx@Wo + qc[t]
    k_ln_generic<<<dim3(MS), 256, 0, stream>>>(bufA, nullptr, ffn_g, ffn_b, ctxh, ctxl); // yln
    k_gemm<3><<<dim3(16, 64), 256, 0, stream>>>(ctxh, ctxl, W1Th, W1Tl, CB, 2 * CB,
        nullptr, h1h, h1l, b1, nullptr, 2 * CB);                      // h1 = gelu(yln@W1+b1)
    k_gemm<4><<<dim3(8, 64), 256, 0, stream>>>(h1h, h1l, W2Th, W2Tl, 2 * CB, CB,
        zp, nullptr, nullptr, b2, bufA, CB);                          // z_pred
    k_rln<<<dim3(MS), 256, 0, stream>>>(bufB, zp, tn_g, tn_b, scale, kvh, kvl);  // sc*tanh(LN(zt-zp))
    k_gemm<5><<<dim3(1, 64), 256, 0, stream>>>(kvh, kvl, WdTh, WdTl, CB, DD,
        rDs, nullptr, nullptr, bd, nullptr, DD);                      // rD
    k_rvq2<<<dim3(MS / 16), 512, 0, stream>>>(rDs, bookFh, bookFl, hn, books, qdh, qdl);
    k_gemm<4><<<dim3(8, 64), 256, 0, stream>>>(qdh, qdl, WuTh, WuTl, 128, CB,
        zp, nullptr, nullptr, bu, zp, CB);                            // z_hat (in place)
    k_tr_out<<<dim3(64, 32, BSL), TB, 0, stream>>>(zp, zrun, carry, b0);
    k_tr_rd<<<dim3(64, 3, BSL), TB, 0, stream>>>(rDs, rtok, b0);
  }

  // ---- pass B: token 0 of every chunk, using carries ----
  float* q0f = bufB;
  float* Q0f = bufB + (size_t)MB * CB;
  k_q0ln<<<dim3(MB), 256, 0, stream>>>(carry, peT, ln_q_g, ln_q_b, q0f, kvh, kvl);
  k_gemm<0><<<dim3(8, 16), 256, 0, stream>>>(kvh, kvl, WqTh, WqTl, CB, CB,
      Q0f, nullptr, nullptr, nullptr, nullptr, CB);
  k_attn<true><<<dim3(NCHK, BBAT, HH), 64, 0, stream>>>(Kbuf, Vbuf, Q0f, ctxh, ctxl, 0);
  k_gemm<2><<<dim3(8, 16), 256, 0, stream>>>(ctxh, ctxl, WoTh, WoTl, CB, CB,
      bufA, nullptr, nullptr, nullptr, q0f, CB);                      // y0 = ctx0@Wo + q0
  k_ln_generic<<<dim3(MB), 256, 0, stream>>>(bufA, nullptr, ffn_g, ffn_b, ctxh, ctxl);
  k_gemm<3><<<dim3(16, 16), 256, 0, stream>>>(ctxh, ctxl, W1Th, W1Tl, CB, 2 * CB,
      nullptr, h1h, h1l, b1, nullptr, 2 * CB);
  k_gemm<4><<<dim3(8, 16), 256, 0, stream>>>(h1h, h1l, W2Th, W2Tl, 2 * CB, CB,
      zp, nullptr, nullptr, b2, bufA, CB);
  k_rln<<<dim3(MB), 256, 0, stream>>>(zt0T, zp, tn_g, tn_b, scale, kvh, kvl);
  k_gemm<5><<<dim3(1, 16), 256, 0, stream>>>(kvh, kvl, WdTh, WdTl, CB, DD,
      rDs, nullptr, nullptr, bd, nullptr, DD);
  k_rvq2<<<dim3(MB / 16), 512, 0, stream>>>(rDs, bookFh, bookFl, hn, books, qdh, qdl);
  k_gemm<4><<<dim3(8, 16), 256, 0, stream>>>(qdh, qdl, WuTh, WuTl, 128, CB,
      zp, nullptr, nullptr, bu, zp, CB);
  k_scat_z<<<dim3(MB, 4), 256, 0, stream>>>(zp, zrun);
  k_scat_r<<<dim3(MB), 128, 0, stream>>>(rDs, rtok);
}